// Round 3
// baseline (193.705 us; speedup 1.0000x reference)
//
#include <hip/hip_runtime.h>

// Problem constants (from reference)
constexpr int B = 512;
constexpr int D = 2048;
constexpr int C = 10000;
constexpr long long ND = (long long)C * D;      // 20,480,000 center elements

// ---------------------------------------------------------------------------
// K1: shifted copy, fully 16B-aligned on BOTH sides.
// out[0] = 0 (loss accumulator), out[1+j] = centers[j].
// dst float4 m covers out[4m..4m+3] = {centers[4m-1], centers[4m..4m+2]}
//   = {prev lane's v.w, v.x, v.y, v.z}, obtained via __shfl_up within the
// 64-lane wave; lane 0 patches with one scalar load. No misaligned vectors.
// ---------------------------------------------------------------------------
__global__ void copy_shift_kernel(const float* __restrict__ centers,
                                  float* __restrict__ out) {
    const long long M = ND / 4;                  // 5,120,000 (exact)
    long long t = (long long)blockIdx.x * blockDim.x + threadIdx.x;
    long long stride = (long long)gridDim.x * blockDim.x;
    const float4* __restrict__ src = reinterpret_cast<const float4*>(centers);
    float4*       __restrict__ dst = reinterpret_cast<float4*>(out);
    const int lane = threadIdx.x & 63;
    for (long long m = t; m < M; m += stride) {
        float4 v = src[m];                       // 16B-aligned load
        float pw = __shfl_up(v.w, 1);            // centers[4m-1] for lane>0
        if (lane == 0) pw = (m > 0) ? centers[4 * m - 1] : 0.0f;
        dst[m] = make_float4(pw, v.x, v.y, v.z); // 16B-aligned store
    }
    if (t == 0) out[ND] = centers[ND - 1];       // final element
}

// ---------------------------------------------------------------------------
// K2: fused rank + loss + center-update. One block per sample; only the
// rank-0 block of each label group proceeds. It computes the closed form
//   new_row = 0.5^k * c + sum_r 0.5^(k-r) * f_r      (alpha = 0.5)
// and the group's loss contribution sum_r ||f_r - c||^2 (original c),
// with ONE atomicAdd(out[0]) per group. No per-element atomics.
// Runs after K1 (separate launch => stream-ordered overwrite of its rows).
// ---------------------------------------------------------------------------
__global__ void group_kernel(const float* __restrict__ features,
                             const int* __restrict__ labels,
                             const float* __restrict__ centers,
                             float* __restrict__ out) {
    const int i = blockIdx.x;
    __shared__ int sl[B];
    __shared__ int mem[B];
    for (int j = threadIdx.x; j < B; j += blockDim.x) sl[j] = labels[j];
    __syncthreads();
    const int l = sl[i];

    // Uniform redundant scan: ordered member list + rank-0 test.
    int k = 0;
    bool rank0 = true;
    for (int j = 0; j < B; ++j) {
        if (sl[j] == l) {
            if (j < i) { rank0 = false; break; }
            mem[k++] = j;                        // all threads write same value
        }
    }
    if (!rank0) return;                          // uniform per block

    const float kc = exp2f(-(float)k);           // 0.5^k (exact)
    const float* __restrict__ crow = centers + (long long)l * D;
    float*       __restrict__ orow = out + 1 + (long long)l * D;
    const int tx = threadIdx.x;

    float cv[8], acc[8];
    float lsum = 0.0f;
#pragma unroll
    for (int jj = 0; jj < 8; ++jj) {
        cv[jj]  = crow[tx + jj * 256];           // coalesced
        acc[jj] = kc * cv[jj];
    }
    for (int r = 0; r < k; ++r) {
        const float* __restrict__ frow = features + (long long)mem[r] * D;
        const float coef = exp2f(-(float)(k - r));   // 0.5^(k-r)
#pragma unroll
        for (int jj = 0; jj < 8; ++jj) {
            float fv = frow[tx + jj * 256];
            float d  = fv - cv[jj];
            lsum    += d * d;
            acc[jj] += coef * fv;
        }
    }
#pragma unroll
    for (int jj = 0; jj < 8; ++jj) orow[tx + jj * 256] = acc[jj];

    // block-reduce loss, one atomic per group
    for (int off = 32; off > 0; off >>= 1) lsum += __shfl_down(lsum, off);
    __shared__ float wsum[4];
    if ((tx & 63) == 0) wsum[tx >> 6] = lsum;
    __syncthreads();
    if (tx == 0) {
        float tot = wsum[0] + wsum[1] + wsum[2] + wsum[3];
        atomicAdd(out, tot * (1.0f / ((float)B * (float)D)));
    }
}

extern "C" void kernel_launch(void* const* d_in, const int* in_sizes, int n_in,
                              void* d_out, int out_size, void* d_ws, size_t ws_size,
                              hipStream_t stream) {
    const float* features = (const float*)d_in[0];
    const int*   labels   = (const int*)d_in[1];
    const float* centers  = (const float*)d_in[2];
    float*       out      = (float*)d_out;

    copy_shift_kernel<<<2048, 256, 0, stream>>>(centers, out);
    group_kernel<<<B, 256, 0, stream>>>(features, labels, centers, out);
}

// Round 4
// 156.628 us; speedup vs baseline: 1.2367x; 1.2367x over previous
//
#include <hip/hip_runtime.h>

constexpr int B = 512;
constexpr int D = 2048;
constexpr int C = 10000;
constexpr long long ND = (long long)C * D;      // 20,480,000
constexpr int BMW = (C + 31) / 32;              // 313 bitmap words
constexpr int NCOPY = 1536;                     // copy-role blocks
// grid = B (group role) + NCOPY (copy role) = 2048 blocks * 4 waves = 8192 waves

// ---------------------------------------------------------------------------
// K0 (tiny): zero the loss slot, build touched-row bitmap in ws.
// ---------------------------------------------------------------------------
__global__ void prep_kernel(const int* __restrict__ labels,
                            float* __restrict__ out,
                            unsigned int* __restrict__ bitmap) {
    __shared__ unsigned int sb[BMW];
    const int tx = threadIdx.x;
    for (int j = tx; j < BMW; j += blockDim.x) sb[j] = 0u;
    __syncthreads();
    int l = labels[tx];
    atomicOr(&sb[l >> 5], 1u << (l & 31));
    __syncthreads();
    for (int j = tx; j < BMW; j += blockDim.x) bitmap[j] = sb[j];
    if (tx == 0) out[0] = 0.0f;
}

// ---------------------------------------------------------------------------
// K1 (fused): blocks [0,B) = group role — closed-form EMA update of the
// touched rows + loss atomics; blocks [B, B+NCOPY) = copy role — shifted,
// 16B-aligned-on-both-sides copy of all UNtouched rows (bitmap skip).
// Write sets are disjoint: copy skips exactly the rows group writes.
// ---------------------------------------------------------------------------
__global__ __launch_bounds__(256) void fused_kernel(
        const float* __restrict__ features,
        const int* __restrict__ labels,
        const float* __restrict__ centers,
        const unsigned int* __restrict__ bitmap,
        float* __restrict__ out) {
    if (blockIdx.x < B) {
        // ----------------- group role: one block per sample -----------------
        const int i = blockIdx.x;
        __shared__ int sl[B];
        __shared__ int mem[B];
        for (int j = threadIdx.x; j < B; j += blockDim.x) sl[j] = labels[j];
        __syncthreads();
        const int l = sl[i];
        int k = 0;
        bool rank0 = true;
        for (int j = 0; j < B; ++j) {
            if (sl[j] == l) {
                if (j < i) { rank0 = false; break; }
                mem[k++] = j;                    // uniform write
            }
        }
        if (!rank0) return;

        const float kc = exp2f(-(float)k);       // 0.5^k
        const float* __restrict__ crow = centers + (long long)l * D;
        float*       __restrict__ orow = out + 1 + (long long)l * D;
        const int tx = threadIdx.x;

        float cv[8], acc[8];
        float lsum = 0.0f;
#pragma unroll
        for (int jj = 0; jj < 8; ++jj) {
            cv[jj]  = crow[tx + jj * 256];
            acc[jj] = kc * cv[jj];
        }
        for (int r = 0; r < k; ++r) {
            const float* __restrict__ frow = features + (long long)mem[r] * D;
            const float coef = exp2f(-(float)(k - r));   // 0.5^(k-r)
#pragma unroll
            for (int jj = 0; jj < 8; ++jj) {
                float fv = frow[tx + jj * 256];
                float d  = fv - cv[jj];
                lsum    += d * d;
                acc[jj] += coef * fv;
            }
        }
#pragma unroll
        for (int jj = 0; jj < 8; ++jj) orow[tx + jj * 256] = acc[jj];

        for (int off = 32; off > 0; off >>= 1) lsum += __shfl_down(lsum, off);
        __shared__ float wsum[4];
        if ((tx & 63) == 0) wsum[tx >> 6] = lsum;
        __syncthreads();
        if (tx == 0) {
            float tot = wsum[0] + wsum[1] + wsum[2] + wsum[3];
            atomicAdd(out, tot * (1.0f / ((float)B * (float)D)));
        }
    } else {
        // ----------------- copy role: shifted aligned copy ------------------
        __shared__ unsigned int sb[BMW];
        for (int j = threadIdx.x; j < BMW; j += 256) sb[j] = bitmap[j];
        __syncthreads();

        const long long M = ND / 4;              // 5,120,000 float4s
        long long t = (long long)(blockIdx.x - B) * 256 + threadIdx.x;
        const long long stride = (long long)NCOPY * 256;
        const int lane = threadIdx.x & 63;
        const float4* __restrict__ src = reinterpret_cast<const float4*>(centers);
        float4*       __restrict__ dst = reinterpret_cast<float4*>(out);

        for (long long m = t; m < M; m += stride) {
            float4 v = src[m];                   // 16B-aligned load
            float pw = __shfl_up(v.w, 1);        // centers[4m-1] for lane>0
            if (lane == 0 && m > 0) pw = centers[4 * m - 1];

            // out[4m]   <- centers[4m-1] : row r0
            // out[4m+1..3] <- centers[4m..4m+2] : row r1 (single row)
            int r1 = (int)((4 * m) >> 11);
            bool t1 = (sb[r1 >> 5] >> (r1 & 31)) & 1u;
            bool t0;
            if (m == 0) {
                t0 = true;                       // out[0] is the loss slot
            } else {
                int r0 = (int)((4 * m - 1) >> 11);
                t0 = (sb[r0 >> 5] >> (r0 & 31)) & 1u;
            }
            if (!t0 && !t1) {
                dst[m] = make_float4(pw, v.x, v.y, v.z);   // aligned store
            } else if (!t0) {
                out[4 * m] = pw;
            } else if (!t1) {
                out[4 * m + 1] = v.x;
                out[4 * m + 2] = v.y;
                out[4 * m + 3] = v.z;
            }
        }
        if (t == 0) {                            // final element out[ND]
            int r = C - 1;
            if (!((sb[r >> 5] >> (r & 31)) & 1u)) out[ND] = centers[ND - 1];
        }
    }
}

extern "C" void kernel_launch(void* const* d_in, const int* in_sizes, int n_in,
                              void* d_out, int out_size, void* d_ws, size_t ws_size,
                              hipStream_t stream) {
    const float* features = (const float*)d_in[0];
    const int*   labels   = (const int*)d_in[1];
    const float* centers  = (const float*)d_in[2];
    float*       out      = (float*)d_out;
    unsigned int* bitmap  = (unsigned int*)d_ws;

    prep_kernel<<<1, B, 0, stream>>>(labels, out, bitmap);
    fused_kernel<<<B + NCOPY, 256, 0, stream>>>(features, labels, centers,
                                                bitmap, out);
}